// Round 3
// baseline (346.722 us; speedup 1.0000x reference)
//
#include <hip/hip_runtime.h>
#include <hip/hip_bf16.h>
#include <stdint.h>

// S=1024, B=4, H=1024, N=16, D=64. Causal relative attention (TXL-style).
// ws layout (MB):
//   0  Xb   bf16 [4096][1024]          (later aliased as AVb)
//   8  Pb   bf16 [8192][1024]
//  24  WT3  bf16 [3072][1024]
//  30  WrT  bf16 [1024][1024]
//  32  Wob  bf16 [1024][1024]
//  34  Qb   bf16 [64bn][1024i][64d]
//  42  Kb   bf16 [64bn][1024j][64d]
//  50  VTb  bf16 [64bn][64d][1024j]
//  58  Rb   bf16 [64bn][1024dist][64d]   R[dist]=kr[S-dist]
//  66  efb  f32  [2][64bn][1024i]                (0.5MB)
//  66.5 dpw u64  [4b][1024i][16jt]               (0.5MB)
//  67  mlp  f32  [2560pid][64row][2(m,l)]        (1.31MB)
//  69  pOb  bf16 [2560pid][64row][64d]           (21MB)

typedef short short8 __attribute__((ext_vector_type(8)));
typedef __bf16 bf16x8 __attribute__((ext_vector_type(8)));
typedef float f32x4 __attribute__((ext_vector_type(4)));
typedef unsigned short u16;
typedef unsigned long long u64;

#define LOG2E 1.4426950408889634f

__device__ __forceinline__ u16 f2bf(float f) {
  union { float f; unsigned u; } v; v.f = f;
  unsigned u = v.u;
  u += 0x7fffu + ((u >> 16) & 1u);
  return (u16)(u >> 16);
}
__device__ __forceinline__ float bf2f(u16 h) {
  union { unsigned u; float f; } v; v.u = ((unsigned)h) << 16;
  return v.f;
}

__device__ __forceinline__ f32x4 MFMA(short8 a, short8 b, f32x4 c) {
  union { short8 s; bf16x8 v; } ua, ub;
  ua.s = a; ub.s = b;
  return __builtin_amdgcn_mfma_f32_16x16x32_bf16(ua.v, ub.v, c, 0, 0, 0);
}

__device__ __forceinline__ void gload16(const void* g, void* l) {
  __builtin_amdgcn_global_load_lds(
      (const __attribute__((address_space(1))) unsigned int*)g,
      (__attribute__((address_space(3))) unsigned int*)l, 16, 0, 0);
}

// ---------------- prep kernels ----------------

__global__ void k_cvt(const float* __restrict__ in, u16* __restrict__ out, int n) {
  int i = (blockIdx.x * blockDim.x + threadIdx.x) * 4;
  if (i >= n) return;
  float4 f = *reinterpret_cast<const float4*>(in + i);
  ushort4 o;
  o.x = f2bf(f.x); o.y = f2bf(f.y); o.z = f2bf(f.z); o.w = f2bf(f.w);
  *reinterpret_cast<ushort4*>(out + i) = o;
}

__global__ void k_transpose(const float* __restrict__ Wq, const float* __restrict__ Wk,
                            const float* __restrict__ Wv, const float* __restrict__ Wr,
                            u16* __restrict__ WT3, u16* __restrict__ WrT) {
  __shared__ float tile[32][33];
  int which = blockIdx.z;
  const float* src = (which == 0) ? Wq : (which == 1) ? Wk : (which == 2) ? Wv : Wr;
  u16* dst = (which < 3) ? (WT3 + (size_t)which * 1048576) : WrT;
  int c0 = blockIdx.x * 32, h0 = blockIdx.y * 32;
  int tx = threadIdx.x, ty = threadIdx.y;  // (32,8)
  for (int r = 0; r < 32; r += 8)
    tile[ty + r][tx] = src[(size_t)(h0 + ty + r) * 1024 + c0 + tx];
  __syncthreads();
  for (int r = 0; r < 32; r += 8)
    dst[(size_t)(c0 + ty + r) * 1024 + h0 + tx] = f2bf(tile[tx][ty + r]);
}

// seg_mat[i,j,b,1] -> bitmask dpw[b][i][jt] (bit jj = diff flag for j = jt*64+jj)
__global__ void k_dpackw(const float* __restrict__ seg, u64* __restrict__ dpw) {
  int idx = blockIdx.x * blockDim.x + threadIdx.x;
  if (idx >= 65536) return;
  int w16 = idx & 15, i = (idx >> 4) & 1023, b = idx >> 14;
  const float* base = seg + ((size_t)((i << 10) + (w16 << 6))) * 8 + b * 2 + 1;
  u64 m = 0;
  for (int jj = 0; jj < 64; jj++)
    if (base[(size_t)jj * 8] != 0.f) m |= (1ull << jj);
  dpw[idx] = m;
}

// ef[s][bn][i] = sum_d (Q[bn][i][d] + r_s_bias[n][d]) * seg_embed[s][n][d]
__global__ void k_ef(const u16* __restrict__ Q, const float* __restrict__ rsb,
                     const float* __restrict__ segE, float* __restrict__ ef) {
  int idx = blockIdx.x * blockDim.x + threadIdx.x;
  if (idx >= 65536) return;
  int i = idx & 1023, bn = idx >> 10, n = bn & 15;
  float s0 = 0.f, s1 = 0.f;
  const u16* qrow = Q + ((size_t)(bn << 10 | i)) * 64;
  for (int d = 0; d < 64; d++) {
    float qv = bf2f(qrow[d]) + rsb[n * 64 + d];
    s0 += qv * segE[n * 64 + d];
    s1 += qv * segE[1024 + n * 64 + d];
  }
  ef[idx] = s0;
  ef[65536 + idx] = s1;
}

// ---------------- GEMM (128x128 tile, BK=32, 4 waves, global_load_lds staging) ----------------

template <int MODE>
__device__ __forceinline__ int srcA(int row, int kk) {
  if (MODE == 0) return row * 1024 + kk;
  if (MODE == 1) return ((1024 - (row >> 2)) * 4 + (row & 3)) * 1024 + kk;
  int i = row >> 2, b = row & 3, n = kk >> 6, d = kk & 63;
  return (((b << 4) | n) * 1024 + i) * 64 + d;
}

template <int MODE>
__global__ __launch_bounds__(256, 2) void k_gemm(const u16* __restrict__ A,
                                                 const u16* __restrict__ L,
                                                 void* __restrict__ out0,
                                                 u16* __restrict__ outK,
                                                 u16* __restrict__ outV) {
  __shared__ u16 At[128 * 32];
  __shared__ u16 Lt[128 * 32];
  int m0 = blockIdx.x * 128, n0 = blockIdx.y * 128;
  int tid = threadIdx.x;
  int w = tid >> 6, lane = tid & 63;
  int lr = lane & 15, lg = lane >> 4;
  int wr = w >> 1, wc = w & 1;
  f32x4 acc[4][4] = {};

  for (int k0 = 0; k0 < 1024; k0 += 32) {
    for (int cc = 0; cc < 2; cc++) {
      int slot = cc * 256 + w * 64 + lane;
      int row = slot >> 2, ch = slot & 3;
      int sch = ch ^ ((row >> 1) & 3);
      gload16(A + srcA<MODE>(m0 + row, k0 + sch * 8), &At[(cc * 256 + w * 64) * 8]);
      gload16(L + (size_t)(n0 + row) * 1024 + k0 + sch * 8, &Lt[(cc * 256 + w * 64) * 8]);
    }
    __syncthreads();
    short8 af[4], bfr[4];
    for (int mt = 0; mt < 4; mt++) {
      int rr = wr * 64 + mt * 16 + lr;
      af[mt] = *reinterpret_cast<const short8*>(&At[rr * 32 + ((lg ^ ((rr >> 1) & 3)) * 8)]);
    }
    for (int ct = 0; ct < 4; ct++) {
      int rr = wc * 64 + ct * 16 + lr;
      bfr[ct] = *reinterpret_cast<const short8*>(&Lt[rr * 32 + ((lg ^ ((rr >> 1) & 3)) * 8)]);
    }
    for (int mt = 0; mt < 4; mt++)
      for (int ct = 0; ct < 4; ct++)
        acc[mt][ct] = MFMA(af[mt], bfr[ct], acc[mt][ct]);
    __syncthreads();
  }

  for (int mt = 0; mt < 4; mt++)
    for (int ct = 0; ct < 4; ct++)
      for (int r = 0; r < 4; r++) {
        int row = m0 + wr * 64 + mt * 16 + lg * 4 + r;
        int col = n0 + wc * 64 + ct * 16 + lr;
        float v = acc[mt][ct][r];
        if (MODE == 0) {
          int i = row >> 2, b = row & 3;
          int which = col >> 10, nd = col & 1023, n = nd >> 6, d = nd & 63;
          u16 hv = f2bf(v);
          int bn = (b << 4) | n;
          if (which == 0)       ((u16*)out0)[(size_t)(bn * 1024 + i) * 64 + d] = hv;
          else if (which == 1)  outK[(size_t)(bn * 1024 + i) * 64 + d] = hv;
          else                  outV[((size_t)(bn * 64 + d) << 10) + i] = hv;
        } else if (MODE == 1) {
          int dist = row >> 2, b = row & 3, n = col >> 6, d = col & 63;
          ((u16*)out0)[(size_t)((((b << 4) | n) * 1024 + dist)) * 64 + d] = f2bf(v);
        } else {
          ((float*)out0)[(size_t)row * 1024 + col] = v;
        }
      }
}

// ---------------- split-KV flash attention ----------------
// grid (40, 64): logical chunk cid within bn, bn. XCD-bijective swizzle of the
// flat id keeps all 40 chunks of ~8 consecutive bn on one XCD's L2.
// BD band alignment is done fully in-register via ds_bpermute (no t_lds).
__global__ __launch_bounds__(256, 4) void k_attn2(
    const u16* __restrict__ Q, const u16* __restrict__ K, const u16* __restrict__ VT,
    const u16* __restrict__ R, const float* __restrict__ ef,
    const u64* __restrict__ dpw, const float* __restrict__ rwb,
    const float* __restrict__ rrb, float* __restrict__ mlp, u16* __restrict__ pO) {
  __shared__ u16 p_lds[4][16][64];
  int f = blockIdx.x + 40 * blockIdx.y;
  int wg = (f & 7) * 320 + (f >> 3);   // 2560 = 8 * 320, bijective
  int bn = wg / 40;
  int cid = wg - bn * 40;
  int b = bn >> 4, n = bn & 15;
  int g = (cid < 4) ? 0 : (cid < 12) ? 1 : (cid < 24) ? 2 : 3;
  int off = cid - 2 * g * (g + 1);
  int qt = 4 * g + off / (g + 1);
  int jc = off % (g + 1);
  int ntiles = (jc < g) ? 4 : (qt + 1 - 4 * g);
  int jt0 = jc * 4;
  int tid = threadIdx.x;
  int w = tid >> 6, lane = tid & 63;
  int lr = lane & 15, lg = lane >> 4;
  int qbase = qt * 64 + w * 16;

  // Q fragments with r_w / r_r biases folded in
  short8 qw[2], qr[2];
  for (int ks = 0; ks < 2; ks++) {
    short8 qv = *reinterpret_cast<const short8*>(
        &Q[(size_t)((bn << 10) + qbase + lr) * 64 + ks * 32 + lg * 8]);
    short8 aa, bb;
    for (int e = 0; e < 8; e++) {
      int d = ks * 32 + lg * 8 + e;
      float fq = bf2f((u16)qv[e]);
      aa[e] = (short)f2bf(fq + rwb[n * 64 + d]);
      bb[e] = (short)f2bf(fq + rrb[n * 64 + d]);
    }
    qw[ks] = aa;
    qr[ks] = bb;
  }
  float e0[4], de[4];
  for (int r = 0; r < 4; r++) {
    int qi = qbase + lg * 4 + r;
    e0[r] = ef[(bn << 10) + qi];
    de[r] = ef[65536 + (bn << 10) + qi] - e0[r];
  }
  float mrow[4], lsum[4];
  f32x4 Oacc[4] = {};
  for (int r = 0; r < 4; r++) { mrow[r] = -3.0e38f; lsum[r] = 0.f; }

  for (int t = 0; t < ntiles; t++) {
    int jt = jt0 + t;
    int j0 = jt * 64;
    // AC scores
    f32x4 sacc[4] = {};
#pragma unroll
    for (int ks = 0; ks < 2; ks++)
#pragma unroll
      for (int ct = 0; ct < 4; ct++) {
        short8 kb = *reinterpret_cast<const short8*>(
            &K[(size_t)((bn << 10) + j0 + ct * 16 + lr) * 64 + ks * 32 + lg * 8]);
        sacc[ct] = MFMA(qw[ks], kb, sacc[ct]);
      }
    // BD band: t[ii][c] = qr_ii . R[band_lo + c], c in [0,80)
    f32x4 tacc[5] = {};
    int band_lo = qbase - j0 - 63;
#pragma unroll
    for (int ks = 0; ks < 2; ks++)
#pragma unroll
      for (int ct = 0; ct < 5; ct++) {
        int ridx = band_lo + ct * 16 + lr;
        ridx = ridx < 0 ? 0 : (ridx > 1023 ? 1023 : ridx);
        short8 rb = *reinterpret_cast<const short8*>(
            &R[(size_t)((bn << 10) + ridx) * 64 + ks * 32 + lg * 8]);
        tacc[ct] = MFMA(qr[ks], rb, tacc[ct]);
      }
    // seg-diff bitmask words (per query row)
    u64 dw[4];
#pragma unroll
    for (int r = 0; r < 4; r++)
      dw[r] = dpw[(size_t)(((b << 10) + qbase + lg * 4 + r)) * 16 + jt];

    // assemble scores in-register: bd[ii][jj] = t[ii][63+ii-jj] via bpermute
    bool diag = (jt == qt);
    float rmax[4] = {-3.0e38f, -3.0e38f, -3.0e38f, -3.0e38f};
#pragma unroll
    for (int ct = 0; ct < 4; ct++) {
      int jj = ct * 16 + lr;
#pragma unroll
      for (int r = 0; r < 4; r++) {
        int ii = lg * 4 + r;
        int cc = 63 + ii - jj;                 // always in [0,78]
        int sl = (lg << 4) | (cc & 15);        // same lg group, permuted lr
        float v0 = __shfl(tacc[3 - ct][r], sl);
        float v1 = __shfl(tacc[4 - ct][r], sl);
        float bd = ((cc >> 4) == 3 - ct) ? v0 : v1;
        float s = sacc[ct][r] + bd + e0[r];
        if ((dw[r] >> jj) & 1) s += de[r];
        s *= 0.125f;
        if (diag && jj > w * 16 + ii) s = -1.0e30f;
        sacc[ct][r] = s;
        rmax[r] = fmaxf(rmax[r], s);
      }
    }
    // online softmax (per-wave)
#pragma unroll
    for (int r = 0; r < 4; r++) {
      float m = rmax[r];
      m = fmaxf(m, __shfl_xor(m, 1));
      m = fmaxf(m, __shfl_xor(m, 2));
      m = fmaxf(m, __shfl_xor(m, 4));
      m = fmaxf(m, __shfl_xor(m, 8));
      float mnew = fmaxf(mrow[r], m);
      float alpha = exp2f((mrow[r] - mnew) * LOG2E);
      mrow[r] = mnew;
      lsum[r] *= alpha;
      Oacc[0][r] *= alpha; Oacc[1][r] *= alpha; Oacc[2][r] *= alpha; Oacc[3][r] *= alpha;
      float rs = 0.f;
#pragma unroll
      for (int ct = 0; ct < 4; ct++) {
        float pf = exp2f((sacc[ct][r] - mnew) * LOG2E);
        sacc[ct][r] = pf;
        rs += pf;
      }
      rs += __shfl_xor(rs, 1); rs += __shfl_xor(rs, 2);
      rs += __shfl_xor(rs, 4); rs += __shfl_xor(rs, 8);
      lsum[r] += rs;
    }
    // P -> LDS bf16, column-chunk XOR swizzle (per-wave region; HW DS in-order,
    // compiler inserts the lgkmcnt for the dependent read)
#pragma unroll
    for (int ct = 0; ct < 4; ct++)
#pragma unroll
      for (int r = 0; r < 4; r++) {
        int ii = lg * 4 + r, jj = ct * 16 + lr;
        p_lds[w][ii][jj ^ ((ii & 7) << 3)] = f2bf(sacc[ct][r]);
      }
    // PV
#pragma unroll
    for (int ks = 0; ks < 2; ks++) {
      int chunk = ks * 4 + lg;
      short8 afr = *reinterpret_cast<const short8*>(&p_lds[w][lr][(chunk ^ (lr & 7)) * 8]);
#pragma unroll
      for (int dt = 0; dt < 4; dt++) {
        short8 vb = *reinterpret_cast<const short8*>(
            &VT[((size_t)((bn << 6) + dt * 16 + lr) << 10) + j0 + ks * 32 + lg * 8]);
        Oacc[dt] = MFMA(afr, vb, Oacc[dt]);
      }
    }
  }

  int pid = bn * 40 + cid;
  if (lr == 0)
#pragma unroll
    for (int r = 0; r < 4; r++) {
      int row = w * 16 + lg * 4 + r;
      mlp[(size_t)pid * 128 + row * 2]     = mrow[r];
      mlp[(size_t)pid * 128 + row * 2 + 1] = lsum[r];
    }
#pragma unroll
  for (int dt = 0; dt < 4; dt++)
#pragma unroll
    for (int r = 0; r < 4; r++) {
      int row = w * 16 + lg * 4 + r;
      pO[(size_t)pid * 4096 + row * 64 + dt * 16 + lr] = f2bf(Oacc[dt][r]);
    }
}

// combine partials: grid (16, 64), block 256
__global__ void k_comb(const float* __restrict__ mlp, const u16* __restrict__ pO,
                       u16* __restrict__ AV) {
  __shared__ float sc[4][64];
  int qt = blockIdx.x, bn = blockIdx.y;
  int g = qt >> 2, nc = g + 1;
  int cbase = 2 * g * (g + 1) + (qt - 4 * g) * (g + 1);
  int pid0 = bn * 40 + cbase;
  int t = threadIdx.x;
  if (t < 64) {
    float mv[4], lv[4];
    float M = -3.0e38f;
    for (int c2 = 0; c2 < 4; c2++) {
      if (c2 < nc) {
        mv[c2] = mlp[(size_t)(pid0 + c2) * 128 + t * 2];
        lv[c2] = mlp[(size_t)(pid0 + c2) * 128 + t * 2 + 1];
      } else { mv[c2] = -3.0e38f; lv[c2] = 0.f; }
      M = fmaxf(M, mv[c2]);
    }
    float L = 0.f;
    float ex[4];
    for (int c2 = 0; c2 < 4; c2++) {
      ex[c2] = exp2f((mv[c2] - M) * LOG2E);
      L += ex[c2] * lv[c2];
    }
    float inv = 1.0f / L;
    for (int c2 = 0; c2 < 4; c2++) sc[c2][t] = ex[c2] * inv;
  }
  __syncthreads();
  int dg = t & 7, rowg = t >> 3;  // 32 rows per pass, 8 d-chunks
  for (int half = 0; half < 2; half++) {
    int ii = half * 32 + rowg;
    float o[8] = {0, 0, 0, 0, 0, 0, 0, 0};
    for (int c2 = 0; c2 < 4; c2++) {
      if (c2 >= nc) break;
      short8 pv = *reinterpret_cast<const short8*>(
          &pO[(size_t)(pid0 + c2) * 4096 + ii * 64 + dg * 8]);
      float s = sc[c2][ii];
      for (int e2 = 0; e2 < 8; e2++) o[e2] += bf2f((u16)pv[e2]) * s;
    }
    short8 ov;
    for (int e2 = 0; e2 < 8; e2++) ov[e2] = (short)f2bf(o[e2]);
    *reinterpret_cast<short8*>(&AV[(size_t)((bn << 10) + qt * 64 + ii) * 64 + dg * 8]) = ov;
  }
}

// ---------------- launch ----------------

extern "C" void kernel_launch(void* const* d_in, const int* in_sizes, int n_in,
                              void* d_out, int out_size, void* d_ws, size_t ws_size,
                              hipStream_t stream) {
  const float* X    = (const float*)d_in[0];
  const float* pos  = (const float*)d_in[1];
  const float* segE = (const float*)d_in[2];
  const float* segM = (const float*)d_in[3];
  const float* rwb  = (const float*)d_in[4];
  const float* rrb  = (const float*)d_in[5];
  const float* rsb  = (const float*)d_in[6];
  const float* Wq = (const float*)d_in[8];
  const float* Wk = (const float*)d_in[9];
  const float* Wv = (const float*)d_in[10];
  const float* Wr = (const float*)d_in[11];
  const float* Wo = (const float*)d_in[12];

  char* ws = (char*)d_ws;
  u16* Xb   = (u16*)(ws);
  u16* Pb   = (u16*)(ws + (8L << 20));
  u16* WT3  = (u16*)(ws + (24L << 20));
  u16* WrT  = (u16*)(ws + (30L << 20));
  u16* Wob  = (u16*)(ws + (32L << 20));
  u16* Qb   = (u16*)(ws + (34L << 20));
  u16* Kb   = (u16*)(ws + (42L << 20));
  u16* VTb  = (u16*)(ws + (50L << 20));
  u16* Rb   = (u16*)(ws + (58L << 20));
  float* efb = (float*)(ws + (66L << 20));
  u64* dpwb = (u64*)(ws + (66L << 20) + (512L << 10));
  float* mlpb = (float*)(ws + (67L << 20));
  u16* pOb  = (u16*)(ws + (69L << 20));
  u16* AVb  = Xb;  // Xb dead after k_gemm<0>

  k_cvt<<<4096, 256, 0, stream>>>(X, Xb, 4194304);
  k_cvt<<<8192, 256, 0, stream>>>(pos, Pb, 8388608);
  k_cvt<<<1024, 256, 0, stream>>>(Wo, Wob, 1048576);
  k_transpose<<<dim3(32, 32, 4), dim3(32, 8), 0, stream>>>(Wq, Wk, Wv, Wr, WT3, WrT);
  k_dpackw<<<256, 256, 0, stream>>>(segM, dpwb);
  k_gemm<0><<<dim3(32, 24), 256, 0, stream>>>(Xb, WT3, Qb, Kb, VTb);
  k_gemm<1><<<dim3(32, 8), 256, 0, stream>>>(Pb, WrT, Rb, nullptr, nullptr);
  k_ef<<<256, 256, 0, stream>>>(Qb, rsb, segE, efb);
  k_attn2<<<dim3(40, 64), 256, 0, stream>>>(Qb, Kb, VTb, Rb, efb, dpwb, rwb, rrb, mlpb, pOb);
  k_comb<<<dim3(16, 64), 256, 0, stream>>>(mlpb, pOb, AVb);
  k_gemm<2><<<dim3(32, 8), 256, 0, stream>>>(AVb, Wob, d_out, nullptr, nullptr);
}

// Round 4
// 262.368 us; speedup vs baseline: 1.3215x; 1.3215x over previous
//
#include <hip/hip_runtime.h>
#include <hip/hip_bf16.h>
#include <stdint.h>

// S=1024, B=4, H=1024, N=16, D=64. Causal relative attention (TXL-style).
// ws layout (MB):
//   0  Xb   bf16 [4096][1024]          (later aliased as AVb)
//   8  Pb   bf16 [8192][1024]
//  24  WT3  bf16 [3072][1024]
//  30  WrT  bf16 [1024][1024]
//  32  Wob  bf16 [1024][1024]
//  34  Qb   bf16 [64bn][1024i][64d]
//  42  Kb   bf16 [64bn][1024j][64d]
//  50  VTb  bf16 [64bn][64d][1024j]
//  58  Rb   bf16 [64bn][1024dist][64d]   R[dist]=kr[S-dist]
//  66  efb  f32  [2][64bn][1024i]                (0.5MB)
//  66.5 dpw u64  [4b][1024i][16jt]               (0.5MB)
//  67  mlp  f32  [2560pid][64row][2(m,l)]        (1.31MB)
//  69  pOb  bf16 [2560pid][64row][64d]           (21MB)

typedef short short8 __attribute__((ext_vector_type(8)));
typedef __bf16 bf16x8 __attribute__((ext_vector_type(8)));
typedef float f32x4 __attribute__((ext_vector_type(4)));
typedef unsigned short u16;
typedef unsigned long long u64;

#define LOG2E 1.4426950408889634f

__device__ __forceinline__ u16 f2bf(float f) {
  union { float f; unsigned u; } v; v.f = f;
  unsigned u = v.u;
  u += 0x7fffu + ((u >> 16) & 1u);
  return (u16)(u >> 16);
}
__device__ __forceinline__ float bf2f(u16 h) {
  union { unsigned u; float f; } v; v.u = ((unsigned)h) << 16;
  return v.f;
}

__device__ __forceinline__ f32x4 MFMA(short8 a, short8 b, f32x4 c) {
  union { short8 s; bf16x8 v; } ua, ub;
  ua.s = a; ub.s = b;
  return __builtin_amdgcn_mfma_f32_16x16x32_bf16(ua.v, ub.v, c, 0, 0, 0);
}

__device__ __forceinline__ void gload16(const void* g, void* l) {
  __builtin_amdgcn_global_load_lds(
      (const __attribute__((address_space(1))) unsigned int*)g,
      (__attribute__((address_space(3))) unsigned int*)l, 16, 0, 0);
}

// ---------------- prep kernels ----------------

__global__ void k_cvt(const float* __restrict__ in, u16* __restrict__ out, int n) {
  int i = (blockIdx.x * blockDim.x + threadIdx.x) * 4;
  if (i >= n) return;
  float4 f = *reinterpret_cast<const float4*>(in + i);
  ushort4 o;
  o.x = f2bf(f.x); o.y = f2bf(f.y); o.z = f2bf(f.z); o.w = f2bf(f.w);
  *reinterpret_cast<ushort4*>(out + i) = o;
}

__global__ void k_transpose(const float* __restrict__ Wq, const float* __restrict__ Wk,
                            const float* __restrict__ Wv, const float* __restrict__ Wr,
                            u16* __restrict__ WT3, u16* __restrict__ WrT) {
  __shared__ float tile[32][33];
  int which = blockIdx.z;
  const float* src = (which == 0) ? Wq : (which == 1) ? Wk : (which == 2) ? Wv : Wr;
  u16* dst = (which < 3) ? (WT3 + (size_t)which * 1048576) : WrT;
  int c0 = blockIdx.x * 32, h0 = blockIdx.y * 32;
  int tx = threadIdx.x, ty = threadIdx.y;  // (32,8)
  for (int r = 0; r < 32; r += 8)
    tile[ty + r][tx] = src[(size_t)(h0 + ty + r) * 1024 + c0 + tx];
  __syncthreads();
  for (int r = 0; r < 32; r += 8)
    dst[(size_t)(c0 + ty + r) * 1024 + h0 + tx] = f2bf(tile[tx][ty + r]);
}

// seg_mat[i,j,b,1] -> bitmask dpw[b][i][jt] (bit jj = diff flag for j = jt*64+jj)
__global__ void k_dpackw(const float* __restrict__ seg, u64* __restrict__ dpw) {
  int idx = blockIdx.x * blockDim.x + threadIdx.x;
  if (idx >= 65536) return;
  int w16 = idx & 15, i = (idx >> 4) & 1023, b = idx >> 14;
  const float* base = seg + ((size_t)((i << 10) + (w16 << 6))) * 8 + b * 2 + 1;
  u64 m = 0;
  for (int jj = 0; jj < 64; jj++)
    if (base[(size_t)jj * 8] != 0.f) m |= (1ull << jj);
  dpw[idx] = m;
}

// ef[s][bn][i] = sum_d (Q[bn][i][d] + r_s_bias[n][d]) * seg_embed[s][n][d]
__global__ void k_ef(const u16* __restrict__ Q, const float* __restrict__ rsb,
                     const float* __restrict__ segE, float* __restrict__ ef) {
  int idx = blockIdx.x * blockDim.x + threadIdx.x;
  if (idx >= 65536) return;
  int i = idx & 1023, bn = idx >> 10, n = bn & 15;
  float s0 = 0.f, s1 = 0.f;
  const u16* qrow = Q + ((size_t)(bn << 10 | i)) * 64;
  for (int d = 0; d < 64; d++) {
    float qv = bf2f(qrow[d]) + rsb[n * 64 + d];
    s0 += qv * segE[n * 64 + d];
    s1 += qv * segE[1024 + n * 64 + d];
  }
  ef[idx] = s0;
  ef[65536 + idx] = s1;
}

// ---------------- GEMM (128x128 tile, BK=32, 4 waves, global_load_lds staging) ----------------

template <int MODE>
__device__ __forceinline__ int srcA(int row, int kk) {
  if (MODE == 0) return row * 1024 + kk;
  if (MODE == 1) return ((1024 - (row >> 2)) * 4 + (row & 3)) * 1024 + kk;
  int i = row >> 2, b = row & 3, n = kk >> 6, d = kk & 63;
  return (((b << 4) | n) * 1024 + i) * 64 + d;
}

template <int MODE>
__global__ __launch_bounds__(256, 2) void k_gemm(const u16* __restrict__ A,
                                                 const u16* __restrict__ L,
                                                 void* __restrict__ out0,
                                                 u16* __restrict__ outK,
                                                 u16* __restrict__ outV) {
  __shared__ u16 At[128 * 32];
  __shared__ u16 Lt[128 * 32];
  int m0 = blockIdx.x * 128, n0 = blockIdx.y * 128;
  int tid = threadIdx.x;
  int w = tid >> 6, lane = tid & 63;
  int lr = lane & 15, lg = lane >> 4;
  int wr = w >> 1, wc = w & 1;
  f32x4 acc[4][4] = {};

  for (int k0 = 0; k0 < 1024; k0 += 32) {
    for (int cc = 0; cc < 2; cc++) {
      int slot = cc * 256 + w * 64 + lane;
      int row = slot >> 2, ch = slot & 3;
      int sch = ch ^ ((row >> 1) & 3);
      gload16(A + srcA<MODE>(m0 + row, k0 + sch * 8), &At[(cc * 256 + w * 64) * 8]);
      gload16(L + (size_t)(n0 + row) * 1024 + k0 + sch * 8, &Lt[(cc * 256 + w * 64) * 8]);
    }
    __syncthreads();
    short8 af[4], bfr[4];
    for (int mt = 0; mt < 4; mt++) {
      int rr = wr * 64 + mt * 16 + lr;
      af[mt] = *reinterpret_cast<const short8*>(&At[rr * 32 + ((lg ^ ((rr >> 1) & 3)) * 8)]);
    }
    for (int ct = 0; ct < 4; ct++) {
      int rr = wc * 64 + ct * 16 + lr;
      bfr[ct] = *reinterpret_cast<const short8*>(&Lt[rr * 32 + ((lg ^ ((rr >> 1) & 3)) * 8)]);
    }
    for (int mt = 0; mt < 4; mt++)
      for (int ct = 0; ct < 4; ct++)
        acc[mt][ct] = MFMA(af[mt], bfr[ct], acc[mt][ct]);
    __syncthreads();
  }

  for (int mt = 0; mt < 4; mt++)
    for (int ct = 0; ct < 4; ct++)
      for (int r = 0; r < 4; r++) {
        int row = m0 + wr * 64 + mt * 16 + lg * 4 + r;
        int col = n0 + wc * 64 + ct * 16 + lr;
        float v = acc[mt][ct][r];
        if (MODE == 0) {
          int i = row >> 2, b = row & 3;
          int which = col >> 10, nd = col & 1023, n = nd >> 6, d = nd & 63;
          u16 hv = f2bf(v);
          int bn = (b << 4) | n;
          if (which == 0)       ((u16*)out0)[(size_t)(bn * 1024 + i) * 64 + d] = hv;
          else if (which == 1)  outK[(size_t)(bn * 1024 + i) * 64 + d] = hv;
          else                  outV[((size_t)(bn * 64 + d) << 10) + i] = hv;
        } else if (MODE == 1) {
          int dist = row >> 2, b = row & 3, n = col >> 6, d = col & 63;
          ((u16*)out0)[(size_t)((((b << 4) | n) * 1024 + dist)) * 64 + d] = f2bf(v);
        } else {
          ((float*)out0)[(size_t)row * 1024 + col] = v;
        }
      }
}

// ---------------- split-KV flash attention ----------------
// grid (40, 64). BD band alignment fully in-register via shuffles (no t_lds).
// launch_bounds(256,2): do NOT cap VGPR below live state (~110-130) — the
// (256,4) variant spilled 175MB to scratch and was 1.6x slower.
__global__ __launch_bounds__(256, 2) void k_attn2(
    const u16* __restrict__ Q, const u16* __restrict__ K, const u16* __restrict__ VT,
    const u16* __restrict__ R, const float* __restrict__ ef,
    const u64* __restrict__ dpw, const float* __restrict__ rwb,
    const float* __restrict__ rrb, float* __restrict__ mlp, u16* __restrict__ pO) {
  __shared__ u16 p_lds[4][16][64];
  int f = blockIdx.x + 40 * blockIdx.y;
  int wg = (f & 7) * 320 + (f >> 3);   // 2560 = 8 * 320, bijective
  int bn = wg / 40;
  int cid = wg - bn * 40;
  int b = bn >> 4, n = bn & 15;
  int g = (cid < 4) ? 0 : (cid < 12) ? 1 : (cid < 24) ? 2 : 3;
  int off = cid - 2 * g * (g + 1);
  int qt = 4 * g + off / (g + 1);
  int jc = off % (g + 1);
  int ntiles = (jc < g) ? 4 : (qt + 1 - 4 * g);
  int jt0 = jc * 4;
  int tid = threadIdx.x;
  int w = tid >> 6, lane = tid & 63;
  int lr = lane & 15, lg = lane >> 4;
  int qbase = qt * 64 + w * 16;

  // Q fragments with r_w / r_r biases folded in
  short8 qw[2], qr[2];
  for (int ks = 0; ks < 2; ks++) {
    short8 qv = *reinterpret_cast<const short8*>(
        &Q[(size_t)((bn << 10) + qbase + lr) * 64 + ks * 32 + lg * 8]);
    short8 aa, bb;
    for (int e = 0; e < 8; e++) {
      int d = ks * 32 + lg * 8 + e;
      float fq = bf2f((u16)qv[e]);
      aa[e] = (short)f2bf(fq + rwb[n * 64 + d]);
      bb[e] = (short)f2bf(fq + rrb[n * 64 + d]);
    }
    qw[ks] = aa;
    qr[ks] = bb;
  }
  float e0[4], de[4];
  for (int r = 0; r < 4; r++) {
    int qi = qbase + lg * 4 + r;
    e0[r] = ef[(bn << 10) + qi];
    de[r] = ef[65536 + (bn << 10) + qi] - e0[r];
  }
  float mrow[4], lsum[4];
  f32x4 Oacc[4] = {};
  for (int r = 0; r < 4; r++) { mrow[r] = -3.0e38f; lsum[r] = 0.f; }

  for (int t = 0; t < ntiles; t++) {
    int jt = jt0 + t;
    int j0 = jt * 64;
    // AC scores
    f32x4 sacc[4] = {};
#pragma unroll
    for (int ks = 0; ks < 2; ks++)
#pragma unroll
      for (int ct = 0; ct < 4; ct++) {
        short8 kb = *reinterpret_cast<const short8*>(
            &K[(size_t)((bn << 10) + j0 + ct * 16 + lr) * 64 + ks * 32 + lg * 8]);
        sacc[ct] = MFMA(qw[ks], kb, sacc[ct]);
      }
    // BD band: t[ii][c] = qr_ii . R[band_lo + c], c in [0,80)
    f32x4 tacc[5] = {};
    int band_lo = qbase - j0 - 63;
#pragma unroll
    for (int ks = 0; ks < 2; ks++)
#pragma unroll
      for (int ct = 0; ct < 5; ct++) {
        int ridx = band_lo + ct * 16 + lr;
        ridx = ridx < 0 ? 0 : (ridx > 1023 ? 1023 : ridx);
        short8 rb = *reinterpret_cast<const short8*>(
            &R[(size_t)((bn << 10) + ridx) * 64 + ks * 32 + lg * 8]);
        tacc[ct] = MFMA(qr[ks], rb, tacc[ct]);
      }
    // seg-diff bitmask words (per query row)
    u64 dw[4];
#pragma unroll
    for (int r = 0; r < 4; r++)
      dw[r] = dpw[(size_t)(((b << 10) + qbase + lg * 4 + r)) * 16 + jt];

    // assemble scores in-register: bd[ii][jj] = t[ii][63+ii-jj] via shuffles
    bool diag = (jt == qt);
    float rmax[4] = {-3.0e38f, -3.0e38f, -3.0e38f, -3.0e38f};
#pragma unroll
    for (int ct = 0; ct < 4; ct++) {
      int jj = ct * 16 + lr;
#pragma unroll
      for (int r = 0; r < 4; r++) {
        int ii = lg * 4 + r;
        int cc = 63 + ii - jj;                 // always in [0,78]
        int sl = (lg << 4) | (cc & 15);        // same lg group, permuted lr
        float v0 = __shfl(tacc[3 - ct][r], sl);
        float v1 = __shfl(tacc[4 - ct][r], sl);
        float bd = ((cc >> 4) == 3 - ct) ? v0 : v1;
        float s = sacc[ct][r] + bd + e0[r];
        if ((dw[r] >> jj) & 1) s += de[r];
        s *= 0.125f;
        if (diag && jj > w * 16 + ii) s = -1.0e30f;
        sacc[ct][r] = s;
        rmax[r] = fmaxf(rmax[r], s);
      }
    }
    // online softmax (per-wave), defer-max: skip rescale when max growth <= 8
#pragma unroll
    for (int r = 0; r < 4; r++) {
      float m = rmax[r];
      m = fmaxf(m, __shfl_xor(m, 1));
      m = fmaxf(m, __shfl_xor(m, 2));
      m = fmaxf(m, __shfl_xor(m, 4));
      m = fmaxf(m, __shfl_xor(m, 8));
      if (m > mrow[r] + 8.0f) {
        float alpha = exp2f((mrow[r] - m) * LOG2E);
        mrow[r] = m;
        lsum[r] *= alpha;
        Oacc[0][r] *= alpha; Oacc[1][r] *= alpha; Oacc[2][r] *= alpha; Oacc[3][r] *= alpha;
      }
      float rs = 0.f;
#pragma unroll
      for (int ct = 0; ct < 4; ct++) {
        float pf = exp2f((sacc[ct][r] - mrow[r]) * LOG2E);
        sacc[ct][r] = pf;
        rs += pf;
      }
      rs += __shfl_xor(rs, 1); rs += __shfl_xor(rs, 2);
      rs += __shfl_xor(rs, 4); rs += __shfl_xor(rs, 8);
      lsum[r] += rs;
    }
    // P -> LDS bf16, column-chunk XOR swizzle (per-wave region; HW DS in-order)
#pragma unroll
    for (int ct = 0; ct < 4; ct++)
#pragma unroll
      for (int r = 0; r < 4; r++) {
        int ii = lg * 4 + r, jj = ct * 16 + lr;
        p_lds[w][ii][jj ^ ((ii & 7) << 3)] = f2bf(sacc[ct][r]);
      }
    // PV
#pragma unroll
    for (int ks = 0; ks < 2; ks++) {
      int chunk = ks * 4 + lg;
      short8 afr = *reinterpret_cast<const short8*>(&p_lds[w][lr][(chunk ^ (lr & 7)) * 8]);
#pragma unroll
      for (int dt = 0; dt < 4; dt++) {
        short8 vb = *reinterpret_cast<const short8*>(
            &VT[((size_t)((bn << 6) + dt * 16 + lr) << 10) + j0 + ks * 32 + lg * 8]);
        Oacc[dt] = MFMA(afr, vb, Oacc[dt]);
      }
    }
  }

  int pid = bn * 40 + cid;
  if (lr == 0)
#pragma unroll
    for (int r = 0; r < 4; r++) {
      int row = w * 16 + lg * 4 + r;
      mlp[(size_t)pid * 128 + row * 2]     = mrow[r];
      mlp[(size_t)pid * 128 + row * 2 + 1] = lsum[r];
    }
#pragma unroll
  for (int dt = 0; dt < 4; dt++)
#pragma unroll
    for (int r = 0; r < 4; r++) {
      int row = w * 16 + lg * 4 + r;
      pO[(size_t)pid * 4096 + row * 64 + dt * 16 + lr] = f2bf(Oacc[dt][r]);
    }
}

// combine partials: grid (16, 64), block 256
__global__ void k_comb(const float* __restrict__ mlp, const u16* __restrict__ pO,
                       u16* __restrict__ AV) {
  __shared__ float sc[4][64];
  int qt = blockIdx.x, bn = blockIdx.y;
  int g = qt >> 2, nc = g + 1;
  int cbase = 2 * g * (g + 1) + (qt - 4 * g) * (g + 1);
  int pid0 = bn * 40 + cbase;
  int t = threadIdx.x;
  if (t < 64) {
    float mv[4], lv[4];
    float M = -3.0e38f;
    for (int c2 = 0; c2 < 4; c2++) {
      if (c2 < nc) {
        mv[c2] = mlp[(size_t)(pid0 + c2) * 128 + t * 2];
        lv[c2] = mlp[(size_t)(pid0 + c2) * 128 + t * 2 + 1];
      } else { mv[c2] = -3.0e38f; lv[c2] = 0.f; }
      M = fmaxf(M, mv[c2]);
    }
    float L = 0.f;
    float ex[4];
    for (int c2 = 0; c2 < 4; c2++) {
      ex[c2] = exp2f((mv[c2] - M) * LOG2E);
      L += ex[c2] * lv[c2];
    }
    float inv = 1.0f / L;
    for (int c2 = 0; c2 < 4; c2++) sc[c2][t] = ex[c2] * inv;
  }
  __syncthreads();
  int dg = t & 7, rowg = t >> 3;  // 32 rows per pass, 8 d-chunks
  for (int half = 0; half < 2; half++) {
    int ii = half * 32 + rowg;
    float o[8] = {0, 0, 0, 0, 0, 0, 0, 0};
    for (int c2 = 0; c2 < 4; c2++) {
      if (c2 >= nc) break;
      short8 pv = *reinterpret_cast<const short8*>(
          &pO[(size_t)(pid0 + c2) * 4096 + ii * 64 + dg * 8]);
      float s = sc[c2][ii];
      for (int e2 = 0; e2 < 8; e2++) o[e2] += bf2f((u16)pv[e2]) * s;
    }
    short8 ov;
    for (int e2 = 0; e2 < 8; e2++) ov[e2] = (short)f2bf(o[e2]);
    *reinterpret_cast<short8*>(&AV[(size_t)((bn << 10) + qt * 64 + ii) * 64 + dg * 8]) = ov;
  }
}

// ---------------- launch ----------------

extern "C" void kernel_launch(void* const* d_in, const int* in_sizes, int n_in,
                              void* d_out, int out_size, void* d_ws, size_t ws_size,
                              hipStream_t stream) {
  const float* X    = (const float*)d_in[0];
  const float* pos  = (const float*)d_in[1];
  const float* segE = (const float*)d_in[2];
  const float* segM = (const float*)d_in[3];
  const float* rwb  = (const float*)d_in[4];
  const float* rrb  = (const float*)d_in[5];
  const float* rsb  = (const float*)d_in[6];
  const float* Wq = (const float*)d_in[8];
  const float* Wk = (const float*)d_in[9];
  const float* Wv = (const float*)d_in[10];
  const float* Wr = (const float*)d_in[11];
  const float* Wo = (const float*)d_in[12];

  char* ws = (char*)d_ws;
  u16* Xb   = (u16*)(ws);
  u16* Pb   = (u16*)(ws + (8L << 20));
  u16* WT3  = (u16*)(ws + (24L << 20));
  u16* WrT  = (u16*)(ws + (30L << 20));
  u16* Wob  = (u16*)(ws + (32L << 20));
  u16* Qb   = (u16*)(ws + (34L << 20));
  u16* Kb   = (u16*)(ws + (42L << 20));
  u16* VTb  = (u16*)(ws + (50L << 20));
  u16* Rb   = (u16*)(ws + (58L << 20));
  float* efb = (float*)(ws + (66L << 20));
  u64* dpwb = (u64*)(ws + (66L << 20) + (512L << 10));
  float* mlpb = (float*)(ws + (67L << 20));
  u16* pOb  = (u16*)(ws + (69L << 20));
  u16* AVb  = Xb;  // Xb dead after k_gemm<0>

  k_cvt<<<4096, 256, 0, stream>>>(X, Xb, 4194304);
  k_cvt<<<8192, 256, 0, stream>>>(pos, Pb, 8388608);
  k_cvt<<<1024, 256, 0, stream>>>(Wo, Wob, 1048576);
  k_transpose<<<dim3(32, 32, 4), dim3(32, 8), 0, stream>>>(Wq, Wk, Wv, Wr, WT3, WrT);
  k_dpackw<<<256, 256, 0, stream>>>(segM, dpwb);
  k_gemm<0><<<dim3(32, 24), 256, 0, stream>>>(Xb, WT3, Qb, Kb, VTb);
  k_gemm<1><<<dim3(32, 8), 256, 0, stream>>>(Pb, WrT, Rb, nullptr, nullptr);
  k_ef<<<256, 256, 0, stream>>>(Qb, rsb, segE, efb);
  k_attn2<<<dim3(40, 64), 256, 0, stream>>>(Qb, Kb, VTb, Rb, efb, dpwb, rwb, rrb, mlpb, pOb);
  k_comb<<<dim3(16, 64), 256, 0, stream>>>(mlpb, pOb, AVb);
  k_gemm<2><<<dim3(32, 8), 256, 0, stream>>>(AVb, Wob, d_out, nullptr, nullptr);
}

// Round 5
// 211.347 us; speedup vs baseline: 1.6405x; 1.2414x over previous
//
#include <hip/hip_runtime.h>
#include <hip/hip_bf16.h>
#include <stdint.h>

// S=1024, B=4, H=1024, N=16, D=64. Causal relative attention (TXL-style).
// ws layout (MB):
//   0  Xb   bf16 [4096][1024]          (later aliased as AVb)
//   8  Pb   bf16 [8192][1024]
//  24  WT3  bf16 [3072][1024]
//  30  WrT  bf16 [1024][1024]
//  32  Wob  bf16 [1024][1024]
//  34  Qb   bf16 [64bn][1024i][64d]
//  42  Kb   bf16 [64bn][1024j][64d]
//  50  VTb  bf16 [64bn][64d][1024j]
//  58  Rb   bf16 [64bn][1024dist][64d]   R[dist]=kr[S-dist]
//  66  efb  f32  [2][64bn][1024i]                (0.5MB)
//  66.5 dpw u64  [4b][1024i][16jt]               (0.5MB)
//  67  mlp  f32  [2560pid][64row][2(m,l)]        (1.31MB)
//  69  pOb  bf16 [2560pid][64row][64d]           (21MB)

typedef short short8 __attribute__((ext_vector_type(8)));
typedef __bf16 bf16x8 __attribute__((ext_vector_type(8)));
typedef float f32x4 __attribute__((ext_vector_type(4)));
typedef unsigned short u16;
typedef unsigned long long u64;

#define LOG2E 1.4426950408889634f

__device__ __forceinline__ u16 f2bf(float f) {
  union { float f; unsigned u; } v; v.f = f;
  unsigned u = v.u;
  u += 0x7fffu + ((u >> 16) & 1u);
  return (u16)(u >> 16);
}
__device__ __forceinline__ float bf2f(u16 h) {
  union { unsigned u; float f; } v; v.u = ((unsigned)h) << 16;
  return v.f;
}

__device__ __forceinline__ f32x4 MFMA(short8 a, short8 b, f32x4 c) {
  union { short8 s; bf16x8 v; } ua, ub;
  ua.s = a; ub.s = b;
  return __builtin_amdgcn_mfma_f32_16x16x32_bf16(ua.v, ub.v, c, 0, 0, 0);
}

__device__ __forceinline__ void gload16(const void* g, void* l) {
  __builtin_amdgcn_global_load_lds(
      (const __attribute__((address_space(1))) unsigned int*)g,
      (__attribute__((address_space(3))) unsigned int*)l, 16, 0, 0);
}

// ---------------- prep kernels ----------------

__global__ void k_cvt(const float* __restrict__ in, u16* __restrict__ out, int n) {
  int i = (blockIdx.x * blockDim.x + threadIdx.x) * 4;
  if (i >= n) return;
  float4 f = *reinterpret_cast<const float4*>(in + i);
  ushort4 o;
  o.x = f2bf(f.x); o.y = f2bf(f.y); o.z = f2bf(f.z); o.w = f2bf(f.w);
  *reinterpret_cast<ushort4*>(out + i) = o;
}

__global__ void k_transpose(const float* __restrict__ Wq, const float* __restrict__ Wk,
                            const float* __restrict__ Wv, const float* __restrict__ Wr,
                            u16* __restrict__ WT3, u16* __restrict__ WrT) {
  __shared__ float tile[32][33];
  int which = blockIdx.z;
  const float* src = (which == 0) ? Wq : (which == 1) ? Wk : (which == 2) ? Wv : Wr;
  u16* dst = (which < 3) ? (WT3 + (size_t)which * 1048576) : WrT;
  int c0 = blockIdx.x * 32, h0 = blockIdx.y * 32;
  int tx = threadIdx.x, ty = threadIdx.y;  // (32,8)
  for (int r = 0; r < 32; r += 8)
    tile[ty + r][tx] = src[(size_t)(h0 + ty + r) * 1024 + c0 + tx];
  __syncthreads();
  for (int r = 0; r < 32; r += 8)
    dst[(size_t)(c0 + ty + r) * 1024 + h0 + tx] = f2bf(tile[tx][ty + r]);
}

// seg_mat[i,j,b,1] -> bitmask dpw[b][i][jt] (bit jj = diff flag for j = jt*64+jj)
__global__ void k_dpackw(const float* __restrict__ seg, u64* __restrict__ dpw) {
  int idx = blockIdx.x * blockDim.x + threadIdx.x;
  if (idx >= 65536) return;
  int w16 = idx & 15, i = (idx >> 4) & 1023, b = idx >> 14;
  const float* base = seg + ((size_t)((i << 10) + (w16 << 6))) * 8 + b * 2 + 1;
  u64 m = 0;
  for (int jj = 0; jj < 64; jj++)
    if (base[(size_t)jj * 8] != 0.f) m |= (1ull << jj);
  dpw[idx] = m;
}

// ef[s][bn][i] = sum_d (Q[bn][i][d] + r_s_bias[n][d]) * seg_embed[s][n][d]
__global__ void k_ef(const u16* __restrict__ Q, const float* __restrict__ rsb,
                     const float* __restrict__ segE, float* __restrict__ ef) {
  int idx = blockIdx.x * blockDim.x + threadIdx.x;
  if (idx >= 65536) return;
  int i = idx & 1023, bn = idx >> 10, n = bn & 15;
  float s0 = 0.f, s1 = 0.f;
  const u16* qrow = Q + ((size_t)(bn << 10 | i)) * 64;
  for (int d = 0; d < 64; d++) {
    float qv = bf2f(qrow[d]) + rsb[n * 64 + d];
    s0 += qv * segE[n * 64 + d];
    s1 += qv * segE[1024 + n * 64 + d];
  }
  ef[idx] = s0;
  ef[65536 + idx] = s1;
}

// ---------------- GEMM (128x128 tile, BK=32, 4 waves, global_load_lds staging) ----------------

template <int MODE>
__device__ __forceinline__ int srcA(int row, int kk) {
  if (MODE == 0) return row * 1024 + kk;
  if (MODE == 1) return ((1024 - (row >> 2)) * 4 + (row & 3)) * 1024 + kk;
  int i = row >> 2, b = row & 3, n = kk >> 6, d = kk & 63;
  return (((b << 4) | n) * 1024 + i) * 64 + d;
}

template <int MODE>
__global__ __launch_bounds__(256, 2) void k_gemm(const u16* __restrict__ A,
                                                 const u16* __restrict__ L,
                                                 void* __restrict__ out0,
                                                 u16* __restrict__ outK,
                                                 u16* __restrict__ outV) {
  __shared__ u16 At[128 * 32];
  __shared__ u16 Lt[128 * 32];
  int m0 = blockIdx.x * 128, n0 = blockIdx.y * 128;
  int tid = threadIdx.x;
  int w = tid >> 6, lane = tid & 63;
  int lr = lane & 15, lg = lane >> 4;
  int wr = w >> 1, wc = w & 1;
  f32x4 acc[4][4] = {};

  for (int k0 = 0; k0 < 1024; k0 += 32) {
    for (int cc = 0; cc < 2; cc++) {
      int slot = cc * 256 + w * 64 + lane;
      int row = slot >> 2, ch = slot & 3;
      int sch = ch ^ ((row >> 1) & 3);
      gload16(A + srcA<MODE>(m0 + row, k0 + sch * 8), &At[(cc * 256 + w * 64) * 8]);
      gload16(L + (size_t)(n0 + row) * 1024 + k0 + sch * 8, &Lt[(cc * 256 + w * 64) * 8]);
    }
    __syncthreads();
    short8 af[4], bfr[4];
    for (int mt = 0; mt < 4; mt++) {
      int rr = wr * 64 + mt * 16 + lr;
      af[mt] = *reinterpret_cast<const short8*>(&At[rr * 32 + ((lg ^ ((rr >> 1) & 3)) * 8)]);
    }
    for (int ct = 0; ct < 4; ct++) {
      int rr = wc * 64 + ct * 16 + lr;
      bfr[ct] = *reinterpret_cast<const short8*>(&Lt[rr * 32 + ((lg ^ ((rr >> 1) & 3)) * 8)]);
    }
    for (int mt = 0; mt < 4; mt++)
      for (int ct = 0; ct < 4; ct++)
        acc[mt][ct] = MFMA(af[mt], bfr[ct], acc[mt][ct]);
    __syncthreads();
  }

  for (int mt = 0; mt < 4; mt++)
    for (int ct = 0; ct < 4; ct++)
      for (int r = 0; r < 4; r++) {
        int row = m0 + wr * 64 + mt * 16 + lg * 4 + r;
        int col = n0 + wc * 64 + ct * 16 + lr;
        float v = acc[mt][ct][r];
        if (MODE == 0) {
          int i = row >> 2, b = row & 3;
          int which = col >> 10, nd = col & 1023, n = nd >> 6, d = nd & 63;
          u16 hv = f2bf(v);
          int bn = (b << 4) | n;
          if (which == 0)       ((u16*)out0)[(size_t)(bn * 1024 + i) * 64 + d] = hv;
          else if (which == 1)  outK[(size_t)(bn * 1024 + i) * 64 + d] = hv;
          else                  outV[((size_t)(bn * 64 + d) << 10) + i] = hv;
        } else if (MODE == 1) {
          int dist = row >> 2, b = row & 3, n = col >> 6, d = col & 63;
          ((u16*)out0)[(size_t)((((b << 4) | n) * 1024 + dist)) * 64 + d] = f2bf(v);
        } else {
          ((float*)out0)[(size_t)row * 1024 + col] = v;
        }
      }
}

// ---------------- split-KV flash attention, 2-phase async LDS pipeline ----------------
// grid (40, 64), XCD-bijective swizzle. Per key tile the block cooperatively
// stages K[64][64], VT[64][64], and the UNION R band [128][64] (4 waves' 80-wide
// bands overlap into 128 consecutive rows) via global_load_lds, double-buffered.
// Sync ledger: one __syncthreads per tile. stage(buf^1,t+1) is issued right
// after the barrier; buffer written at iter t was last READ at iter t-1, and
// those reads complete before the iter-t barrier. vmcnt(0) before the barrier
// guarantees staged data landed.
// LDS XOR swizzle (G4): 128B-stride rows -> chunk ^= (row&7); applied as
// pre-swizzled GLOBAL source (linear LDS dest, rule 21) + swizzled ds_read.
__global__ __launch_bounds__(256, 2) void k_attn3(
    const u16* __restrict__ Q, const u16* __restrict__ K, const u16* __restrict__ VT,
    const u16* __restrict__ R, const float* __restrict__ ef,
    const u64* __restrict__ dpw, const float* __restrict__ rwb,
    const float* __restrict__ rrb, float* __restrict__ mlp, u16* __restrict__ pO) {
  __shared__ u16 sK[2][64][64];
  __shared__ u16 sV[2][64][64];
  __shared__ u16 sR[2][128][64];
  __shared__ u16 p_lds[4][16][64];
  int f = blockIdx.x + 40 * blockIdx.y;
  int wg = (f & 7) * 320 + (f >> 3);   // 2560 = 8 * 320, bijective
  int bn = wg / 40;
  int cid = wg - bn * 40;
  int b = bn >> 4, n = bn & 15;
  int g = (cid < 4) ? 0 : (cid < 12) ? 1 : (cid < 24) ? 2 : 3;
  int off = cid - 2 * g * (g + 1);
  int qt = 4 * g + off / (g + 1);
  int jc = off % (g + 1);
  int ntiles = (jc < g) ? 4 : (qt + 1 - 4 * g);
  int jt0 = jc * 4;
  int tid = threadIdx.x;
  int w = tid >> 6, lane = tid & 63;
  int lr = lane & 15, lg = lane >> 4;
  int qbase = qt * 64 + w * 16;
  int sub = lane >> 3, ch = lane & 7;
  int cs = (ch ^ sub) * 8;   // pre-swizzled source chunk offset (elements)
  int r8 = lr & 7;

  // ---- stage(buf, j0): issue 8 async 1KB global->LDS copies per wave ----
  auto stage = [&](int bi, int j0) {
    int rbase = qt * 64 - j0 - 63;   // R phys row pr -> global dist row rbase+pr
#pragma unroll
    for (int q = 0; q < 2; q++) {
      int row = w * 16 + q * 8 + sub;
      gload16(K + (size_t)((bn << 10) + j0 + row) * 64 + cs, &sK[bi][w * 16 + q * 8][0]);
      gload16(VT + (((size_t)((bn << 6) + row)) << 10) + j0 + cs, &sV[bi][w * 16 + q * 8][0]);
    }
#pragma unroll
    for (int q = 0; q < 4; q++) {
      int pr = w * 32 + q * 8 + sub;
      int ridx = rbase + pr;
      ridx = ridx < 0 ? 0 : (ridx > 1023 ? 1023 : ridx);  // garbage rows only feed masked slots
      gload16(R + (size_t)((bn << 10) + ridx) * 64 + cs, &sR[bi][w * 32 + q * 8][0]);
    }
  };

  stage(0, jt0 * 64);  // prologue prefetch (latency hides under Q-frag setup)

  // Q fragments with r_w / r_r biases folded in
  short8 qw[2], qr[2];
  for (int ks = 0; ks < 2; ks++) {
    short8 qv = *reinterpret_cast<const short8*>(
        &Q[(size_t)((bn << 10) + qbase + lr) * 64 + ks * 32 + lg * 8]);
    short8 aa, bb;
    for (int e = 0; e < 8; e++) {
      int d = ks * 32 + lg * 8 + e;
      float fq = bf2f((u16)qv[e]);
      aa[e] = (short)f2bf(fq + rwb[n * 64 + d]);
      bb[e] = (short)f2bf(fq + rrb[n * 64 + d]);
    }
    qw[ks] = aa;
    qr[ks] = bb;
  }
  float e0[4], de[4];
  for (int r = 0; r < 4; r++) {
    int qi = qbase + lg * 4 + r;
    e0[r] = ef[(bn << 10) + qi];
    de[r] = ef[65536 + (bn << 10) + qi] - e0[r];
  }
  float mrow[4], lsum[4];
  f32x4 Oacc[4] = {};
  for (int r = 0; r < 4; r++) { mrow[r] = -3.0e38f; lsum[r] = 0.f; }

  for (int t = 0; t < ntiles; t++) {
    int jt = jt0 + t;
    int j0 = jt * 64;
    int bi = t & 1;
    asm volatile("s_waitcnt vmcnt(0)" ::: "memory");  // staged buf[bi] landed
    __syncthreads();                                   // + all waves done with buf[bi^1]
    if (t + 1 < ntiles) stage(bi ^ 1, j0 + 64);        // async prefetch next tile

    // seg-diff bitmask words (independent loads, issue early)
    u64 dw[4];
#pragma unroll
    for (int r = 0; r < 4; r++)
      dw[r] = dpw[(size_t)(((b << 10) + qbase + lg * 4 + r)) * 16 + jt];

    // AC + BD MFMA cluster from LDS
    f32x4 sacc[4] = {};
    f32x4 tacc[5] = {};
    __builtin_amdgcn_s_setprio(1);
#pragma unroll
    for (int ks = 0; ks < 2; ks++) {
#pragma unroll
      for (int ct = 0; ct < 4; ct++) {
        short8 kb = *reinterpret_cast<const short8*>(
            &sK[bi][ct * 16 + lr][((ks * 4 + lg) ^ r8) * 8]);
        sacc[ct] = MFMA(qw[ks], kb, sacc[ct]);
      }
#pragma unroll
      for (int ct = 0; ct < 5; ct++) {
        short8 rb = *reinterpret_cast<const short8*>(
            &sR[bi][w * 16 + ct * 16 + lr][((ks * 4 + lg) ^ r8) * 8]);
        tacc[ct] = MFMA(qr[ks], rb, tacc[ct]);
      }
    }
    __builtin_amdgcn_s_setprio(0);

    // shear: bd[ii][jj] = t[ii][63+ii-jj] via in-register shuffles
    bool diag = (jt == qt);
    float rmax[4] = {-3.0e38f, -3.0e38f, -3.0e38f, -3.0e38f};
#pragma unroll
    for (int ct = 0; ct < 4; ct++) {
      int jj = ct * 16 + lr;
#pragma unroll
      for (int r = 0; r < 4; r++) {
        int ii = lg * 4 + r;
        int cc = 63 + ii - jj;                 // in [0,78]
        int sl = (lg << 4) | (cc & 15);
        float v0 = __shfl(tacc[3 - ct][r], sl);
        float v1 = __shfl(tacc[4 - ct][r], sl);
        float bd = ((cc >> 4) == 3 - ct) ? v0 : v1;
        float s = sacc[ct][r] + bd + e0[r];
        if ((dw[r] >> jj) & 1) s += de[r];
        s *= 0.125f;
        if (diag && jj > w * 16 + ii) s = -1.0e30f;
        sacc[ct][r] = s;
        rmax[r] = fmaxf(rmax[r], s);
      }
    }
    // online softmax (per-wave), defer-max THR=8
#pragma unroll
    for (int r = 0; r < 4; r++) {
      float m = rmax[r];
      m = fmaxf(m, __shfl_xor(m, 1));
      m = fmaxf(m, __shfl_xor(m, 2));
      m = fmaxf(m, __shfl_xor(m, 4));
      m = fmaxf(m, __shfl_xor(m, 8));
      if (m > mrow[r] + 8.0f) {
        float alpha = exp2f((mrow[r] - m) * LOG2E);
        mrow[r] = m;
        lsum[r] *= alpha;
        Oacc[0][r] *= alpha; Oacc[1][r] *= alpha; Oacc[2][r] *= alpha; Oacc[3][r] *= alpha;
      }
      float rs = 0.f;
#pragma unroll
      for (int ct = 0; ct < 4; ct++) {
        float pf = exp2f((sacc[ct][r] - mrow[r]) * LOG2E);
        sacc[ct][r] = pf;
        rs += pf;
      }
      rs += __shfl_xor(rs, 1); rs += __shfl_xor(rs, 2);
      rs += __shfl_xor(rs, 4); rs += __shfl_xor(rs, 8);
      lsum[r] += rs;
    }
    // P -> LDS bf16 (per-wave region, XOR swizzle, measured conflict-free)
#pragma unroll
    for (int ct = 0; ct < 4; ct++)
#pragma unroll
      for (int r = 0; r < 4; r++) {
        int ii = lg * 4 + r, jj = ct * 16 + lr;
        p_lds[w][ii][jj ^ ((ii & 7) << 3)] = f2bf(sacc[ct][r]);
      }
    // PV from staged sV
    __builtin_amdgcn_s_setprio(1);
#pragma unroll
    for (int ks = 0; ks < 2; ks++) {
      int chunk = ks * 4 + lg;
      short8 afr = *reinterpret_cast<const short8*>(&p_lds[w][lr][(chunk ^ (lr & 7)) * 8]);
#pragma unroll
      for (int dt = 0; dt < 4; dt++) {
        short8 vb = *reinterpret_cast<const short8*>(
            &sV[bi][dt * 16 + lr][((ks * 4 + lg) ^ r8) * 8]);
        Oacc[dt] = MFMA(afr, vb, Oacc[dt]);
      }
    }
    __builtin_amdgcn_s_setprio(0);
  }

  int pid = bn * 40 + cid;
  if (lr == 0)
#pragma unroll
    for (int r = 0; r < 4; r++) {
      int row = w * 16 + lg * 4 + r;
      mlp[(size_t)pid * 128 + row * 2]     = mrow[r];
      mlp[(size_t)pid * 128 + row * 2 + 1] = lsum[r];
    }
#pragma unroll
  for (int dt = 0; dt < 4; dt++)
#pragma unroll
    for (int r = 0; r < 4; r++) {
      int row = w * 16 + lg * 4 + r;
      pO[(size_t)pid * 4096 + row * 64 + dt * 16 + lr] = f2bf(Oacc[dt][r]);
    }
}

// combine partials: grid (16, 64), block 256
__global__ void k_comb(const float* __restrict__ mlp, const u16* __restrict__ pO,
                       u16* __restrict__ AV) {
  __shared__ float sc[4][64];
  int qt = blockIdx.x, bn = blockIdx.y;
  int g = qt >> 2, nc = g + 1;
  int cbase = 2 * g * (g + 1) + (qt - 4 * g) * (g + 1);
  int pid0 = bn * 40 + cbase;
  int t = threadIdx.x;
  if (t < 64) {
    float mv[4], lv[4];
    float M = -3.0e38f;
    for (int c2 = 0; c2 < 4; c2++) {
      if (c2 < nc) {
        mv[c2] = mlp[(size_t)(pid0 + c2) * 128 + t * 2];
        lv[c2] = mlp[(size_t)(pid0 + c2) * 128 + t * 2 + 1];
      } else { mv[c2] = -3.0e38f; lv[c2] = 0.f; }
      M = fmaxf(M, mv[c2]);
    }
    float L = 0.f;
    float ex[4];
    for (int c2 = 0; c2 < 4; c2++) {
      ex[c2] = exp2f((mv[c2] - M) * LOG2E);
      L += ex[c2] * lv[c2];
    }
    float inv = 1.0f / L;
    for (int c2 = 0; c2 < 4; c2++) sc[c2][t] = ex[c2] * inv;
  }
  __syncthreads();
  int dg = t & 7, rowg = t >> 3;  // 32 rows per pass, 8 d-chunks
  for (int half = 0; half < 2; half++) {
    int ii = half * 32 + rowg;
    float o[8] = {0, 0, 0, 0, 0, 0, 0, 0};
    for (int c2 = 0; c2 < 4; c2++) {
      if (c2 >= nc) break;
      short8 pv = *reinterpret_cast<const short8*>(
          &pO[(size_t)(pid0 + c2) * 4096 + ii * 64 + dg * 8]);
      float s = sc[c2][ii];
      for (int e2 = 0; e2 < 8; e2++) o[e2] += bf2f((u16)pv[e2]) * s;
    }
    short8 ov;
    for (int e2 = 0; e2 < 8; e2++) ov[e2] = (short)f2bf(o[e2]);
    *reinterpret_cast<short8*>(&AV[(size_t)((bn << 10) + qt * 64 + ii) * 64 + dg * 8]) = ov;
  }
}

// ---------------- launch ----------------

extern "C" void kernel_launch(void* const* d_in, const int* in_sizes, int n_in,
                              void* d_out, int out_size, void* d_ws, size_t ws_size,
                              hipStream_t stream) {
  const float* X    = (const float*)d_in[0];
  const float* pos  = (const float*)d_in[1];
  const float* segE = (const float*)d_in[2];
  const float* segM = (const float*)d_in[3];
  const float* rwb  = (const float*)d_in[4];
  const float* rrb  = (const float*)d_in[5];
  const float* rsb  = (const float*)d_in[6];
  const float* Wq = (const float*)d_in[8];
  const float* Wk = (const float*)d_in[9];
  const float* Wv = (const float*)d_in[10];
  const float* Wr = (const float*)d_in[11];
  const float* Wo = (const float*)d_in[12];

  char* ws = (char*)d_ws;
  u16* Xb   = (u16*)(ws);
  u16* Pb   = (u16*)(ws + (8L << 20));
  u16* WT3  = (u16*)(ws + (24L << 20));
  u16* WrT  = (u16*)(ws + (30L << 20));
  u16* Wob  = (u16*)(ws + (32L << 20));
  u16* Qb   = (u16*)(ws + (34L << 20));
  u16* Kb   = (u16*)(ws + (42L << 20));
  u16* VTb  = (u16*)(ws + (50L << 20));
  u16* Rb   = (u16*)(ws + (58L << 20));
  float* efb = (float*)(ws + (66L << 20));
  u64* dpwb = (u64*)(ws + (66L << 20) + (512L << 10));
  float* mlpb = (float*)(ws + (67L << 20));
  u16* pOb  = (u16*)(ws + (69L << 20));
  u16* AVb  = Xb;  // Xb dead after k_gemm<0>

  k_cvt<<<4096, 256, 0, stream>>>(X, Xb, 4194304);
  k_cvt<<<8192, 256, 0, stream>>>(pos, Pb, 8388608);
  k_cvt<<<1024, 256, 0, stream>>>(Wo, Wob, 1048576);
  k_transpose<<<dim3(32, 32, 4), dim3(32, 8), 0, stream>>>(Wq, Wk, Wv, Wr, WT3, WrT);
  k_dpackw<<<256, 256, 0, stream>>>(segM, dpwb);
  k_gemm<0><<<dim3(32, 24), 256, 0, stream>>>(Xb, WT3, Qb, Kb, VTb);
  k_gemm<1><<<dim3(32, 8), 256, 0, stream>>>(Pb, WrT, Rb, nullptr, nullptr);
  k_ef<<<256, 256, 0, stream>>>(Qb, rsb, segE, efb);
  k_attn3<<<dim3(40, 64), 256, 0, stream>>>(Qb, Kb, VTb, Rb, efb, dpwb, rwb, rrb, mlpb, pOb);
  k_comb<<<dim3(16, 64), 256, 0, stream>>>(mlpb, pOb, AVb);
  k_gemm<2><<<dim3(32, 8), 256, 0, stream>>>(AVb, Wob, d_out, nullptr, nullptr);
}